// Round 5
// baseline (262.255 us; speedup 1.0000x reference)
//
#include <hip/hip_runtime.h>
#include <hip/hip_bf16.h>

#define NN 512      // nodes per graph
#define NE 8192     // edges per graph
#define NG 128      // graphs (B*G)
#define FH 128      // feature/hidden dim
#define FQ 16       // feature slice per gather block (8 slices)
#define NSEG 64     // edge-balanced node segments per graph
#define BN_EPS 1e-5f

__device__ inline void f4acc(float4& a, const float4& b) {
    a.x += b.x; a.y += b.y; a.z += b.z; a.w += b.w;
}

// ---------------- K1: degrees + norms + CSR build + edge-balanced segments ----------------
__global__ __launch_bounds__(1024) void k_build(const int* __restrict__ edges,
                                                float* __restrict__ rs_out,
                                                float* __restrict__ rs_in,
                                                int* __restrict__ row_ofs,
                                                int* __restrict__ csr_src,
                                                int* __restrict__ seg) {
    int g = blockIdx.x;
    int tid = threadIdx.x;
    const int* src = edges + (size_t)g * 2 * NE;
    const int* dst = src + NE;

    __shared__ int degO[NN], degI[NN];
    __shared__ int scanA[NN], scanB[NN];
    __shared__ int fill[NN];
    __shared__ int csr_lds[NE];          // 32 KB

    for (int i = tid; i < NN; i += 1024) { degO[i] = 0; degI[i] = 0; }
    __syncthreads();
    for (int u = tid; u < NE / 4; u += 1024) {
        int4 s = ((const int4*)src)[u];
        int4 d = ((const int4*)dst)[u];
        atomicAdd(&degO[s.x], 1); atomicAdd(&degO[s.y], 1);
        atomicAdd(&degO[s.z], 1); atomicAdd(&degO[s.w], 1);
        atomicAdd(&degI[d.x], 1); atomicAdd(&degI[d.y], 1);
        atomicAdd(&degI[d.z], 1); atomicAdd(&degI[d.w], 1);
    }
    __syncthreads();
    for (int i = tid; i < NN; i += 1024) {
        int dO = degO[i], dI = degI[i];
        rs_out[g * NN + i] = rsqrtf((float)max(dO, 1));
        rs_in [g * NN + i] = rsqrtf((float)max(dI, 1));
        scanA[i] = dI;
    }
    __syncthreads();
    // Hillis-Steele inclusive scan over 512 in-degrees
    int* sA = scanA; int* sB = scanB;
    for (int off = 1; off < NN; off <<= 1) {
        for (int i = tid; i < NN; i += 1024) {
            int v = sA[i];
            if (i >= off) v += sA[i - off];
            sB[i] = v;
        }
        __syncthreads();
        int* t = sA; sA = sB; sB = t;
    }
    for (int i = tid; i < NN; i += 1024) {
        int excl = (i == 0) ? 0 : sA[i - 1];
        fill[i] = excl;
        row_ofs[g * 513 + i] = excl;
    }
    if (tid == 0) row_ofs[g * 513 + NN] = sA[NN - 1];
    // edge-balanced segments
    if (tid < NSEG) {
        int target = tid * (NE / NSEG);
        int lo = 0, hi = NN;
        while (lo < hi) {
            int mid = (lo + hi) >> 1;
            int ex = (mid == 0) ? 0 : sA[mid - 1];
            if (ex >= target) hi = mid; else lo = mid + 1;
        }
        seg[g * (NSEG + 1) + tid] = lo;
    }
    if (tid == 0) seg[g * (NSEG + 1) + NSEG] = NN;
    __syncthreads();
    for (int u = tid; u < NE / 4; u += 1024) {
        int4 s = ((const int4*)src)[u];
        int4 d = ((const int4*)dst)[u];
        int p0 = atomicAdd(&fill[d.x], 1); csr_lds[p0] = s.x;
        int p1 = atomicAdd(&fill[d.y], 1); csr_lds[p1] = s.y;
        int p2 = atomicAdd(&fill[d.z], 1); csr_lds[p2] = s.z;
        int p3 = atomicAdd(&fill[d.w], 1); csr_lds[p3] = s.w;
    }
    __syncthreads();
    for (int u = tid; u < NE / 4; u += 1024)
        ((int4*)(csr_src + (size_t)g * NE))[u] = ((const int4*)csr_lds)[u];
}

// ---------------- K2/K4: Y = (X @ W) * rs_row  (fp32, 64-row tiles) ----------------
__device__ inline void fma4(float4& a, float s, const float4& w) {
    a.x += s * w.x; a.y += s * w.y; a.z += s * w.z; a.w += s * w.w;
}

__global__ __launch_bounds__(256) void k_gemm(const float* __restrict__ X,
                                              const float* __restrict__ W,
                                              const float* __restrict__ rs,
                                              float* __restrict__ Y) {
    __shared__ float xs[64][FH];   // 32 KB
    int tid = threadIdx.x;
    size_t r0 = (size_t)blockIdx.x * 64;

    const float4* Xv = (const float4*)(X + r0 * FH);
    float4* xsv = (float4*)&xs[0][0];
#pragma unroll
    for (int i = 0; i < 8; i++) xsv[tid + i * 256] = Xv[tid + i * 256];
    __syncthreads();

    int tx = tid & 31;
    int ty = tid >> 5;
    int c4 = tx * 4;
    int row0 = ty * 8;

    float4 acc[8];
#pragma unroll
    for (int i = 0; i < 8; i++) acc[i] = make_float4(0.f, 0.f, 0.f, 0.f);

    // register double-buffered W prefetch: load->use distance = full 4-k sub-tile
    float4 wA[4], wB[4];
#pragma unroll
    for (int j = 0; j < 4; j++) wA[j] = *(const float4*)(W + (size_t)j * FH + c4);

#pragma unroll
    for (int k = 0; k < FH; k += 8) {
#pragma unroll
        for (int j = 0; j < 4; j++) wB[j] = *(const float4*)(W + (size_t)(k + 4 + j) * FH + c4);
#pragma unroll
        for (int i = 0; i < 8; i++) {
            float4 xv = *(const float4*)&xs[row0 + i][k];
            fma4(acc[i], xv.x, wA[0]);
            fma4(acc[i], xv.y, wA[1]);
            fma4(acc[i], xv.z, wA[2]);
            fma4(acc[i], xv.w, wA[3]);
        }
        if (k + 8 < FH) {
#pragma unroll
            for (int j = 0; j < 4; j++) wA[j] = *(const float4*)(W + (size_t)(k + 8 + j) * FH + c4);
        }
#pragma unroll
        for (int i = 0; i < 8; i++) {
            float4 xv = *(const float4*)&xs[row0 + i][k + 4];
            fma4(acc[i], xv.x, wB[0]);
            fma4(acc[i], xv.y, wB[1]);
            fma4(acc[i], xv.z, wB[2]);
            fma4(acc[i], xv.w, wB[3]);
        }
    }

#pragma unroll
    for (int i = 0; i < 8; i++) {
        size_t r = r0 + row0 + i;
        float s = rs[r];
        float4 v = acc[i];
        v.x *= s; v.y *= s; v.z *= s; v.w *= s;
        *(float4*)(Y + r * FH + c4) = v;
    }
}

// ---------------- K3: LDS-staged gather, all metadata in LDS, shfl index bcast ----------------
// Block = (graph, 16-feature slice). 64 groups of 4 lanes; group walks one
// edge-balanced node segment; lane owns 4 consecutive feats.
__global__ __launch_bounds__(256) void k_gather(const float* __restrict__ Y,
                                                const int* __restrict__ row_ofs,
                                                const int* __restrict__ csr_src,
                                                const int* __restrict__ seg,
                                                const float* __restrict__ rs_in,
                                                const float* __restrict__ bias,
                                                float* __restrict__ H) {
    int g  = blockIdx.x;
    int fq = blockIdx.y;   // 0..7
    int tid = threadIdx.x;
    int l4  = tid & 3;
    int grp = tid >> 2;    // 0..63
    int lane = tid & 63;
    int lbase = lane & ~3;

    __shared__ float ys[NN][FQ];     // 32 KB
    __shared__ int   ro_s[NN + 1];   // 2052 B
    __shared__ float rsin_s[NN];     // 2 KB
    __shared__ int   sg_s[NSEG + 1];

    const float* Yg = Y + (size_t)g * NN * FH + fq * FQ;
#pragma unroll
    for (int i = 0; i < 8; i++) {
        int u = tid + i * 256;     // 2048 float4 units
        int r = u >> 2, c = u & 3;
        *(float4*)&ys[r][c * 4] = *(const float4*)(Yg + (size_t)r * FH + c * 4);
    }
    for (int i = tid; i < NN + 1; i += 256) ro_s[i] = row_ofs[g * 513 + i];
    for (int i = tid; i < NN; i += 256) rsin_s[i] = rs_in[g * NN + i];
    if (tid < NSEG + 1) sg_s[tid] = seg[g * (NSEG + 1) + tid];
    __syncthreads();

    const int* cs = csr_src + (size_t)g * NE;
    float4 bv = *(const float4*)(bias + fq * FQ + l4 * 4);
    float* Hg = H + (size_t)g * NN * FH + fq * FQ;

    int d0 = sg_s[grp], d1 = sg_s[grp + 1];
    for (int d = d0; d < d1; d++) {
        int e0 = ro_s[d], e1 = ro_s[d + 1];
        float4 a0 = make_float4(0.f,0.f,0.f,0.f), a1 = a0, a2 = a0, a3 = a0;
        int e = e0;
        for (; e + 4 <= e1; e += 4) {
            int myi = cs[e + l4];                 // coalesced: 1 dword/lane
            int s0 = __shfl(myi, lbase + 0, 64);  // group lanes are convergent
            int s1 = __shfl(myi, lbase + 1, 64);
            int s2 = __shfl(myi, lbase + 2, 64);
            int s3 = __shfl(myi, lbase + 3, 64);
            f4acc(a0, *(float4*)&ys[s0][l4 * 4]);
            f4acc(a1, *(float4*)&ys[s1][l4 * 4]);
            f4acc(a2, *(float4*)&ys[s2][l4 * 4]);
            f4acc(a3, *(float4*)&ys[s3][l4 * 4]);
        }
        for (; e < e1; e++) f4acc(a0, *(float4*)&ys[cs[e]][l4 * 4]);
        float4 s;
        s.x = (a0.x + a1.x) + (a2.x + a3.x);
        s.y = (a0.y + a1.y) + (a2.y + a3.y);
        s.z = (a0.z + a1.z) + (a2.z + a3.z);
        s.w = (a0.w + a1.w) + (a2.w + a3.w);
        float r = rsin_s[d];
        float4 h;
        h.x = fmaxf(r * s.x + bv.x, 0.f);
        h.y = fmaxf(r * s.y + bv.y, 0.f);
        h.z = fmaxf(r * s.z + bv.z, 0.f);
        h.w = fmaxf(r * s.w + bv.w, 0.f);
        *(float4*)(Hg + (size_t)d * FH + l4 * 4) = h;
    }
}

// ---------------- K5: LDS-staged gather2 + fused node-sum -> emb slice ----------------
__global__ __launch_bounds__(256) void k_gather_mean(const float* __restrict__ Y,
                                                     const int* __restrict__ row_ofs,
                                                     const int* __restrict__ csr_src,
                                                     const int* __restrict__ seg,
                                                     const float* __restrict__ rs_in,
                                                     const float* __restrict__ bias,
                                                     float* __restrict__ emb) {
    int g  = blockIdx.x;
    int fq = blockIdx.y;
    int tid = threadIdx.x;
    int l4  = tid & 3;
    int grp = tid >> 2;
    int lane = tid & 63;
    int lbase = lane & ~3;

    __shared__ float ys[NN][FQ];     // 32 KB
    __shared__ int   ro_s[NN + 1];
    __shared__ float rsin_s[NN];
    __shared__ int   sg_s[NSEG + 1];
    __shared__ float4 red[NSEG][4];  // 4 KB

    const float* Yg = Y + (size_t)g * NN * FH + fq * FQ;
#pragma unroll
    for (int i = 0; i < 8; i++) {
        int u = tid + i * 256;
        int r = u >> 2, c = u & 3;
        *(float4*)&ys[r][c * 4] = *(const float4*)(Yg + (size_t)r * FH + c * 4);
    }
    for (int i = tid; i < NN + 1; i += 256) ro_s[i] = row_ofs[g * 513 + i];
    for (int i = tid; i < NN; i += 256) rsin_s[i] = rs_in[g * NN + i];
    if (tid < NSEG + 1) sg_s[tid] = seg[g * (NSEG + 1) + tid];
    __syncthreads();

    const int* cs = csr_src + (size_t)g * NE;
    float4 bv = *(const float4*)(bias + fq * FQ + l4 * 4);

    float4 sum = make_float4(0.f,0.f,0.f,0.f);
    int d0 = sg_s[grp], d1 = sg_s[grp + 1];
    for (int d = d0; d < d1; d++) {
        int e0 = ro_s[d], e1 = ro_s[d + 1];
        float4 a0 = make_float4(0.f,0.f,0.f,0.f), a1 = a0, a2 = a0, a3 = a0;
        int e = e0;
        for (; e + 4 <= e1; e += 4) {
            int myi = cs[e + l4];
            int s0 = __shfl(myi, lbase + 0, 64);
            int s1 = __shfl(myi, lbase + 1, 64);
            int s2 = __shfl(myi, lbase + 2, 64);
            int s3 = __shfl(myi, lbase + 3, 64);
            f4acc(a0, *(float4*)&ys[s0][l4 * 4]);
            f4acc(a1, *(float4*)&ys[s1][l4 * 4]);
            f4acc(a2, *(float4*)&ys[s2][l4 * 4]);
            f4acc(a3, *(float4*)&ys[s3][l4 * 4]);
        }
        for (; e < e1; e++) f4acc(a0, *(float4*)&ys[cs[e]][l4 * 4]);
        float4 s;
        s.x = (a0.x + a1.x) + (a2.x + a3.x);
        s.y = (a0.y + a1.y) + (a2.y + a3.y);
        s.z = (a0.z + a1.z) + (a2.z + a3.z);
        s.w = (a0.w + a1.w) + (a2.w + a3.w);
        float r = rsin_s[d];
        sum.x += fmaxf(r * s.x + bv.x, 0.f);
        sum.y += fmaxf(r * s.y + bv.y, 0.f);
        sum.z += fmaxf(r * s.z + bv.z, 0.f);
        sum.w += fmaxf(r * s.w + bv.w, 0.f);
    }

    red[grp][l4] = sum;
    __syncthreads();
    if (tid < 4) {
        float4 t = red[0][tid];
#pragma unroll
        for (int j = 1; j < NSEG; j++) f4acc(t, red[j][tid]);
        *(float4*)(emb + (size_t)g * FH + fq * FQ + tid * 4) = t;
    }
}

// ---------------- K6: z = emb/512 @ Wt + bt; BN eval; relu ----------------
__global__ __launch_bounds__(128) void k_head(const float* __restrict__ emb,
                                              const float* __restrict__ Wt,
                                              const float* __restrict__ bt,
                                              const float* __restrict__ gamma,
                                              const float* __restrict__ beta,
                                              const float* __restrict__ rmean,
                                              const float* __restrict__ rvar,
                                              float* __restrict__ out) {
    int g = blockIdx.x;
    int j = threadIdx.x;
    __shared__ float e[FH];
    e[j] = emb[(size_t)g * FH + j] * (1.0f / (float)NN);
    __syncthreads();
    float acc = bt[j];
#pragma unroll 8
    for (int k = 0; k < FH; k++) acc += e[k] * Wt[(size_t)k * FH + j];
    float z = gamma[j] * (acc - rmean[j]) * rsqrtf(rvar[j] + BN_EPS) + beta[j];
    out[g * FH + j] = fmaxf(z, 0.f);
}

extern "C" void kernel_launch(void* const* d_in, const int* in_sizes, int n_in,
                              void* d_out, int out_size, void* d_ws, size_t ws_size,
                              hipStream_t stream) {
    const float* feats = (const float*)d_in[0];
    const int*   edges = (const int*)d_in[1];
    const float* W0    = (const float*)d_in[2];
    const float* b0    = (const float*)d_in[3];
    const float* W1    = (const float*)d_in[4];
    const float* b1    = (const float*)d_in[5];
    const float* Wt    = (const float*)d_in[6];
    const float* bt    = (const float*)d_in[7];
    const float* gamma = (const float*)d_in[8];
    const float* beta  = (const float*)d_in[9];
    const float* rmean = (const float*)d_in[10];
    const float* rvar  = (const float*)d_in[11];
    float* out = (float*)d_out;

    // workspace layout
    char* w = (char*)d_ws;
    float* rs_out  = (float*)w;                     w += sizeof(float) * NG * NN;
    float* rs_in   = (float*)w;                     w += sizeof(float) * NG * NN;
    int*   row_ofs = (int*)w;                       w += sizeof(int) * NG * 520;
    int*   seg     = (int*)w;                       w += sizeof(int) * NG * (NSEG + 1);
    int*   csr_src = (int*)w;                       w += sizeof(int) * (size_t)NG * NE;
    float* Y       = (float*)w;                     w += sizeof(float) * (size_t)NG * NN * FH;
    float* H1      = (float*)w;                     w += sizeof(float) * (size_t)NG * NN * FH;
    float* emb     = (float*)w;                     w += sizeof(float) * NG * FH;

    k_build<<<NG, 1024, 0, stream>>>(edges, rs_out, rs_in, row_ofs, csr_src, seg);

    k_gemm<<<(NG * NN) / 64, 256, 0, stream>>>(feats, W0, rs_out, Y);

    k_gather<<<dim3(NG, FH / FQ), 256, 0, stream>>>(Y, row_ofs, csr_src, seg, rs_in, b0, H1);

    k_gemm<<<(NG * NN) / 64, 256, 0, stream>>>(H1, W1, rs_out, Y);

    k_gather_mean<<<dim3(NG, FH / FQ), 256, 0, stream>>>(Y, row_ofs, csr_src, seg, rs_in, b1, emb);

    k_head<<<NG, 128, 0, stream>>>(emb, Wt, bt, gamma, beta, rmean, rvar, out);

    (void)in_sizes; (void)n_in; (void)out_size; (void)ws_size;
}

// Round 6
// 246.989 us; speedup vs baseline: 1.0618x; 1.0618x over previous
//
#include <hip/hip_runtime.h>
#include <hip/hip_bf16.h>

#define NN 512      // nodes per graph
#define NE 8192     // edges per graph
#define NG 128      // graphs (B*G)
#define FH 128      // feature/hidden dim
#define FQ 16       // feature slice per gather block (8 slices)
#define NSEG 64     // edge-balanced node segments per graph
#define BN_EPS 1e-5f

__device__ inline void f4acc(float4& a, const float4& b) {
    a.x += b.x; a.y += b.y; a.z += b.z; a.w += b.w;
}

// ---------------- K1: degrees + norms + CSR (src+dst) build + segments ----------------
__global__ __launch_bounds__(1024) void k_build(const int* __restrict__ edges,
                                                float* __restrict__ rs_out,
                                                float* __restrict__ rs_in,
                                                int* __restrict__ row_ofs,
                                                int* __restrict__ csr_src,
                                                int* __restrict__ csr_dst,
                                                int* __restrict__ seg) {
    int g = blockIdx.x;
    int tid = threadIdx.x;
    const int* src = edges + (size_t)g * 2 * NE;
    const int* dst = src + NE;

    __shared__ int degO[NN], degI[NN];
    __shared__ int scanA[NN], scanB[NN];
    __shared__ int fill[NN];
    __shared__ int csr_lds[NE];          // 32 KB
    __shared__ int dst_lds[NE];          // 32 KB

    for (int i = tid; i < NN; i += 1024) { degO[i] = 0; degI[i] = 0; }
    __syncthreads();
    for (int u = tid; u < NE / 4; u += 1024) {
        int4 s = ((const int4*)src)[u];
        int4 d = ((const int4*)dst)[u];
        atomicAdd(&degO[s.x], 1); atomicAdd(&degO[s.y], 1);
        atomicAdd(&degO[s.z], 1); atomicAdd(&degO[s.w], 1);
        atomicAdd(&degI[d.x], 1); atomicAdd(&degI[d.y], 1);
        atomicAdd(&degI[d.z], 1); atomicAdd(&degI[d.w], 1);
    }
    __syncthreads();
    for (int i = tid; i < NN; i += 1024) {
        int dO = degO[i], dI = degI[i];
        rs_out[g * NN + i] = rsqrtf((float)max(dO, 1));
        rs_in [g * NN + i] = rsqrtf((float)max(dI, 1));
        scanA[i] = dI;
    }
    __syncthreads();
    // Hillis-Steele inclusive scan over 512 in-degrees
    int* sA = scanA; int* sB = scanB;
    for (int off = 1; off < NN; off <<= 1) {
        for (int i = tid; i < NN; i += 1024) {
            int v = sA[i];
            if (i >= off) v += sA[i - off];
            sB[i] = v;
        }
        __syncthreads();
        int* t = sA; sA = sB; sB = t;
    }
    for (int i = tid; i < NN; i += 1024) {
        int excl = (i == 0) ? 0 : sA[i - 1];
        fill[i] = excl;
        row_ofs[g * 513 + i] = excl;
    }
    if (tid == 0) row_ofs[g * 513 + NN] = sA[NN - 1];
    // edge-balanced, row-aligned segments
    if (tid < NSEG) {
        int target = tid * (NE / NSEG);
        int lo = 0, hi = NN;
        while (lo < hi) {
            int mid = (lo + hi) >> 1;
            int ex = (mid == 0) ? 0 : sA[mid - 1];
            if (ex >= target) hi = mid; else lo = mid + 1;
        }
        seg[g * (NSEG + 1) + tid] = lo;
    }
    if (tid == 0) seg[g * (NSEG + 1) + NSEG] = NN;
    __syncthreads();
    for (int u = tid; u < NE / 4; u += 1024) {
        int4 s = ((const int4*)src)[u];
        int4 d = ((const int4*)dst)[u];
        int p0 = atomicAdd(&fill[d.x], 1); csr_lds[p0] = s.x; dst_lds[p0] = d.x;
        int p1 = atomicAdd(&fill[d.y], 1); csr_lds[p1] = s.y; dst_lds[p1] = d.y;
        int p2 = atomicAdd(&fill[d.z], 1); csr_lds[p2] = s.z; dst_lds[p2] = d.z;
        int p3 = atomicAdd(&fill[d.w], 1); csr_lds[p3] = s.w; dst_lds[p3] = d.w;
    }
    __syncthreads();
    for (int u = tid; u < NE / 4; u += 1024) {
        ((int4*)(csr_src + (size_t)g * NE))[u] = ((const int4*)csr_lds)[u];
        ((int4*)(csr_dst + (size_t)g * NE))[u] = ((const int4*)dst_lds)[u];
    }
    // init overshoot pad (prefetch reads up to 8 ints past the last slab)
    if (g == NG - 1 && tid < 8) {
        csr_src[(size_t)NG * NE + tid] = 0;
        csr_dst[(size_t)NG * NE + tid] = 0;
    }
}

// ---------------- K2/K4: Y = (X @ W) * rs_row  (fp32, 64-row tiles, reg-dbuf W) ----------------
__device__ inline void fma4(float4& a, float s, const float4& w) {
    a.x += s * w.x; a.y += s * w.y; a.z += s * w.z; a.w += s * w.w;
}

__global__ __launch_bounds__(256) void k_gemm(const float* __restrict__ X,
                                              const float* __restrict__ W,
                                              const float* __restrict__ rs,
                                              float* __restrict__ Y) {
    __shared__ float xs[64][FH];   // 32 KB
    int tid = threadIdx.x;
    size_t r0 = (size_t)blockIdx.x * 64;

    const float4* Xv = (const float4*)(X + r0 * FH);
    float4* xsv = (float4*)&xs[0][0];
#pragma unroll
    for (int i = 0; i < 8; i++) xsv[tid + i * 256] = Xv[tid + i * 256];
    __syncthreads();

    int tx = tid & 31;
    int ty = tid >> 5;
    int c4 = tx * 4;
    int row0 = ty * 8;

    float4 acc[8];
#pragma unroll
    for (int i = 0; i < 8; i++) acc[i] = make_float4(0.f, 0.f, 0.f, 0.f);

    float4 wA[4], wB[4];
#pragma unroll
    for (int j = 0; j < 4; j++) wA[j] = *(const float4*)(W + (size_t)j * FH + c4);

#pragma unroll
    for (int k = 0; k < FH; k += 8) {
#pragma unroll
        for (int j = 0; j < 4; j++) wB[j] = *(const float4*)(W + (size_t)(k + 4 + j) * FH + c4);
#pragma unroll
        for (int i = 0; i < 8; i++) {
            float4 xv = *(const float4*)&xs[row0 + i][k];
            fma4(acc[i], xv.x, wA[0]);
            fma4(acc[i], xv.y, wA[1]);
            fma4(acc[i], xv.z, wA[2]);
            fma4(acc[i], xv.w, wA[3]);
        }
        if (k + 8 < FH) {
#pragma unroll
            for (int j = 0; j < 4; j++) wA[j] = *(const float4*)(W + (size_t)(k + 8 + j) * FH + c4);
        }
#pragma unroll
        for (int i = 0; i < 8; i++) {
            float4 xv = *(const float4*)&xs[row0 + i][k + 4];
            fma4(acc[i], xv.x, wB[0]);
            fma4(acc[i], xv.y, wB[1]);
            fma4(acc[i], xv.z, wB[2]);
            fma4(acc[i], xv.w, wB[3]);
        }
    }

#pragma unroll
    for (int i = 0; i < 8; i++) {
        size_t r = r0 + row0 + i;
        float s = rs[r];
        float4 v = acc[i];
        v.x *= s; v.y *= s; v.z *= s; v.w *= s;
        *(float4*)(Y + r * FH + c4) = v;
    }
}

// ---------------- K3: flat edge-quad gather ----------------
// Block = (graph, 16-feature slice). 64 groups of 4 lanes; group walks its
// row-aligned edge segment as uniform 4-edge quads; row boundaries flushed
// inline via dst compare; empty rows emit relu(b).
__global__ __launch_bounds__(256) void k_gather(const float* __restrict__ Y,
                                                const int* __restrict__ row_ofs,
                                                const int* __restrict__ csr_src,
                                                const int* __restrict__ csr_dst,
                                                const int* __restrict__ seg,
                                                const float* __restrict__ rs_in,
                                                const float* __restrict__ bias,
                                                float* __restrict__ H) {
    int g  = blockIdx.x;
    int fq = blockIdx.y;   // 0..7
    int tid = threadIdx.x;
    int l4  = tid & 3;
    int grp = tid >> 2;    // 0..63

    __shared__ float ys[NN][FQ];     // 32 KB
    __shared__ float rsin_s[NN];     // 2 KB

    const float* Yg = Y + (size_t)g * NN * FH + fq * FQ;
#pragma unroll
    for (int i = 0; i < 8; i++) {
        int u = tid + i * 256;
        int r = u >> 2, c = u & 3;
        *(float4*)&ys[r][c * 4] = *(const float4*)(Yg + (size_t)r * FH + c * 4);
    }
    for (int i = tid; i < NN; i += 256) rsin_s[i] = rs_in[g * NN + i];
    __syncthreads();

    int d0 = seg[g * (NSEG + 1) + grp], d1 = seg[g * (NSEG + 1) + grp + 1];
    if (d0 >= d1) return;   // no barriers after this point

    const int* ro = row_ofs + g * 513;
    const int* cs = csr_src + (size_t)g * NE;
    const int* cd = csr_dst + (size_t)g * NE;
    int e0 = ro[d0], eEnd = ro[d1];
    float4 bv = *(const float4*)(bias + fq * FQ + l4 * 4);
    float4 rb;  // relu(b): value for empty rows
    rb.x = fmaxf(bv.x, 0.f); rb.y = fmaxf(bv.y, 0.f);
    rb.z = fmaxf(bv.z, 0.f); rb.w = fmaxf(bv.w, 0.f);
    float* Hg = H + (size_t)g * NN * FH + fq * FQ + l4 * 4;

    int d = d0;
    float4 acc = make_float4(0.f, 0.f, 0.f, 0.f);
    int e = e0 & ~3;
    int4 S = *(const int4*)(cs + e);
    int4 D = *(const int4*)(cd + e);
    for (; e < eEnd; e += 4) {
        int4 Sn = *(const int4*)(cs + e + 4);   // padded: always safe
        int4 Dn = *(const int4*)(cd + e + 4);
        float4 y0 = *(float4*)&ys[S.x][l4 * 4];
        float4 y1 = *(float4*)&ys[S.y][l4 * 4];
        float4 y2 = *(float4*)&ys[S.z][l4 * 4];
        float4 y3 = *(float4*)&ys[S.w][l4 * 4];
#define STEP(J, DJ, YJ)                                                     \
        {                                                                   \
            int idx = e + (J);                                              \
            bool valid = (idx >= e0) & (idx < eEnd);                        \
            if (valid && (DJ) != d) {                                       \
                float r = rsin_s[d];                                        \
                float4 h;                                                   \
                h.x = fmaxf(fmaf(r, acc.x, bv.x), 0.f);                     \
                h.y = fmaxf(fmaf(r, acc.y, bv.y), 0.f);                     \
                h.z = fmaxf(fmaf(r, acc.z, bv.z), 0.f);                     \
                h.w = fmaxf(fmaf(r, acc.w, bv.w), 0.f);                     \
                *(float4*)(Hg + (size_t)d * FH) = h;                        \
                for (int dd = d + 1; dd < (DJ); dd++)                       \
                    *(float4*)(Hg + (size_t)dd * FH) = rb;                  \
                d = (DJ);                                                   \
                acc = make_float4(0.f, 0.f, 0.f, 0.f);                      \
            }                                                               \
            if (valid) f4acc(acc, YJ);                                      \
        }
        STEP(0, D.x, y0) STEP(1, D.y, y1) STEP(2, D.z, y2) STEP(3, D.w, y3)
#undef STEP
        S = Sn; D = Dn;
    }
    // final flush: current row d, then trailing empty rows up to d1-1
    {
        float r = rsin_s[d];
        float4 h;
        h.x = fmaxf(fmaf(r, acc.x, bv.x), 0.f);
        h.y = fmaxf(fmaf(r, acc.y, bv.y), 0.f);
        h.z = fmaxf(fmaf(r, acc.z, bv.z), 0.f);
        h.w = fmaxf(fmaf(r, acc.w, bv.w), 0.f);
        *(float4*)(Hg + (size_t)d * FH) = h;
        for (int dd = d + 1; dd < d1; dd++)
            *(float4*)(Hg + (size_t)dd * FH) = rb;
    }
}

// ---------------- K5: flat edge-quad gather2 + fused node-sum -> emb slice ----------------
__global__ __launch_bounds__(256) void k_gather_mean(const float* __restrict__ Y,
                                                     const int* __restrict__ row_ofs,
                                                     const int* __restrict__ csr_src,
                                                     const int* __restrict__ csr_dst,
                                                     const int* __restrict__ seg,
                                                     const float* __restrict__ rs_in,
                                                     const float* __restrict__ bias,
                                                     float* __restrict__ emb) {
    int g  = blockIdx.x;
    int fq = blockIdx.y;
    int tid = threadIdx.x;
    int l4  = tid & 3;
    int grp = tid >> 2;

    __shared__ float ys[NN][FQ];     // 32 KB
    __shared__ float rsin_s[NN];     // 2 KB
    __shared__ float4 red[NSEG][4];  // 4 KB

    const float* Yg = Y + (size_t)g * NN * FH + fq * FQ;
#pragma unroll
    for (int i = 0; i < 8; i++) {
        int u = tid + i * 256;
        int r = u >> 2, c = u & 3;
        *(float4*)&ys[r][c * 4] = *(const float4*)(Yg + (size_t)r * FH + c * 4);
    }
    for (int i = tid; i < NN; i += 256) rsin_s[i] = rs_in[g * NN + i];
    __syncthreads();

    int d0 = seg[g * (NSEG + 1) + grp], d1 = seg[g * (NSEG + 1) + grp + 1];

    const int* ro = row_ofs + g * 513;
    const int* cs = csr_src + (size_t)g * NE;
    const int* cd = csr_dst + (size_t)g * NE;
    float4 bv = *(const float4*)(bias + fq * FQ + l4 * 4);
    float4 rb;
    rb.x = fmaxf(bv.x, 0.f); rb.y = fmaxf(bv.y, 0.f);
    rb.z = fmaxf(bv.z, 0.f); rb.w = fmaxf(bv.w, 0.f);

    float4 sum = make_float4(0.f, 0.f, 0.f, 0.f);
    if (d0 < d1) {
        int e0 = ro[d0], eEnd = ro[d1];
        int d = d0;
        float4 acc = make_float4(0.f, 0.f, 0.f, 0.f);
        int e = e0 & ~3;
        int4 S = *(const int4*)(cs + e);
        int4 D = *(const int4*)(cd + e);
        for (; e < eEnd; e += 4) {
            int4 Sn = *(const int4*)(cs + e + 4);
            int4 Dn = *(const int4*)(cd + e + 4);
            float4 y0 = *(float4*)&ys[S.x][l4 * 4];
            float4 y1 = *(float4*)&ys[S.y][l4 * 4];
            float4 y2 = *(float4*)&ys[S.z][l4 * 4];
            float4 y3 = *(float4*)&ys[S.w][l4 * 4];
#define STEP(J, DJ, YJ)                                                     \
            {                                                               \
                int idx = e + (J);                                          \
                bool valid = (idx >= e0) & (idx < eEnd);                    \
                if (valid && (DJ) != d) {                                   \
                    float r = rsin_s[d];                                    \
                    sum.x += fmaxf(fmaf(r, acc.x, bv.x), 0.f);              \
                    sum.y += fmaxf(fmaf(r, acc.y, bv.y), 0.f);              \
                    sum.z += fmaxf(fmaf(r, acc.z, bv.z), 0.f);              \
                    sum.w += fmaxf(fmaf(r, acc.w, bv.w), 0.f);              \
                    float gf = (float)((DJ) - d - 1);                       \
                    sum.x += gf * rb.x; sum.y += gf * rb.y;                 \
                    sum.z += gf * rb.z; sum.w += gf * rb.w;                 \
                    d = (DJ);                                               \
                    acc = make_float4(0.f, 0.f, 0.f, 0.f);                  \
                }                                                           \
                if (valid) f4acc(acc, YJ);                                  \
            }
            STEP(0, D.x, y0) STEP(1, D.y, y1) STEP(2, D.z, y2) STEP(3, D.w, y3)
#undef STEP
            S = Sn; D = Dn;
        }
        {   // final flush + trailing empties
            float r = rsin_s[d];
            sum.x += fmaxf(fmaf(r, acc.x, bv.x), 0.f);
            sum.y += fmaxf(fmaf(r, acc.y, bv.y), 0.f);
            sum.z += fmaxf(fmaf(r, acc.z, bv.z), 0.f);
            sum.w += fmaxf(fmaf(r, acc.w, bv.w), 0.f);
            float gf = (float)(d1 - 1 - d);
            sum.x += gf * rb.x; sum.y += gf * rb.y;
            sum.z += gf * rb.z; sum.w += gf * rb.w;
        }
    }

    red[grp][l4] = sum;
    __syncthreads();
    if (tid < 4) {
        float4 t = red[0][tid];
#pragma unroll
        for (int j = 1; j < NSEG; j++) f4acc(t, red[j][tid]);
        *(float4*)(emb + (size_t)g * FH + fq * FQ + tid * 4) = t;
    }
}

// ---------------- K6: z = emb/512 @ Wt + bt; BN eval; relu ----------------
__global__ __launch_bounds__(128) void k_head(const float* __restrict__ emb,
                                              const float* __restrict__ Wt,
                                              const float* __restrict__ bt,
                                              const float* __restrict__ gamma,
                                              const float* __restrict__ beta,
                                              const float* __restrict__ rmean,
                                              const float* __restrict__ rvar,
                                              float* __restrict__ out) {
    int g = blockIdx.x;
    int j = threadIdx.x;
    __shared__ float e[FH];
    e[j] = emb[(size_t)g * FH + j] * (1.0f / (float)NN);
    __syncthreads();
    float acc = bt[j];
#pragma unroll 8
    for (int k = 0; k < FH; k++) acc += e[k] * Wt[(size_t)k * FH + j];
    float z = gamma[j] * (acc - rmean[j]) * rsqrtf(rvar[j] + BN_EPS) + beta[j];
    out[g * FH + j] = fmaxf(z, 0.f);
}

extern "C" void kernel_launch(void* const* d_in, const int* in_sizes, int n_in,
                              void* d_out, int out_size, void* d_ws, size_t ws_size,
                              hipStream_t stream) {
    const float* feats = (const float*)d_in[0];
    const int*   edges = (const int*)d_in[1];
    const float* W0    = (const float*)d_in[2];
    const float* b0    = (const float*)d_in[3];
    const float* W1    = (const float*)d_in[4];
    const float* b1    = (const float*)d_in[5];
    const float* Wt    = (const float*)d_in[6];
    const float* bt    = (const float*)d_in[7];
    const float* gamma = (const float*)d_in[8];
    const float* beta  = (const float*)d_in[9];
    const float* rmean = (const float*)d_in[10];
    const float* rvar  = (const float*)d_in[11];
    float* out = (float*)d_out;

    // workspace layout
    char* w = (char*)d_ws;
    float* rs_out  = (float*)w;   w += sizeof(float) * NG * NN;
    float* rs_in   = (float*)w;   w += sizeof(float) * NG * NN;
    int*   row_ofs = (int*)w;     w += sizeof(int) * NG * 520;
    int*   seg     = (int*)w;     w += sizeof(int) * NG * (NSEG + 1) + 64;
    int*   csr_src = (int*)w;     w += sizeof(int) * ((size_t)NG * NE + 16);
    int*   csr_dst = (int*)w;     w += sizeof(int) * ((size_t)NG * NE + 16);
    float* Y       = (float*)w;   w += sizeof(float) * (size_t)NG * NN * FH;
    float* H1      = (float*)w;   w += sizeof(float) * (size_t)NG * NN * FH;
    float* emb     = (float*)w;   w += sizeof(float) * NG * FH;

    k_build<<<NG, 1024, 0, stream>>>(edges, rs_out, rs_in, row_ofs, csr_src, csr_dst, seg);

    k_gemm<<<(NG * NN) / 64, 256, 0, stream>>>(feats, W0, rs_out, Y);

    k_gather<<<dim3(NG, FH / FQ), 256, 0, stream>>>(Y, row_ofs, csr_src, csr_dst, seg, rs_in, b0, H1);

    k_gemm<<<(NG * NN) / 64, 256, 0, stream>>>(H1, W1, rs_out, Y);

    k_gather_mean<<<dim3(NG, FH / FQ), 256, 0, stream>>>(Y, row_ofs, csr_src, csr_dst, seg, rs_in, b1, emb);

    k_head<<<NG, 128, 0, stream>>>(emb, Wt, bt, gamma, beta, rmean, rvar, out);

    (void)in_sizes; (void)n_in; (void)out_size; (void)ws_size;
}

// Round 7
// 216.325 us; speedup vs baseline: 1.2123x; 1.1418x over previous
//
#include <hip/hip_runtime.h>
#include <hip/hip_bf16.h>

#define NN 512      // nodes per graph
#define NE 8192     // edges per graph
#define NG 128      // graphs (B*G)
#define FH 128      // feature/hidden dim
#define FQ 16       // feature slice per gather block (8 slices)
#define NSEG 64     // edge-balanced node segments per graph
#define BN_EPS 1e-5f

typedef __attribute__((ext_vector_type(8))) short s8v;   // 8 bf16 = 4 VGPRs
typedef __attribute__((ext_vector_type(4))) float f4v;   // MFMA C/D

__device__ inline void f4acc(float4& a, const float4& b) {
    a.x += b.x; a.y += b.y; a.z += b.z; a.w += b.w;
}

__device__ inline unsigned short f2bf(float x) {   // RNE fp32 -> bf16 bits
    unsigned u = __float_as_uint(x);
    unsigned r = (u + 0x7fffu + ((u >> 16) & 1u)) >> 16;
    return (unsigned short)r;
}
__device__ inline float bf2f(unsigned short h) { return __uint_as_float(((unsigned)h) << 16); }

// ---------------- K1: degrees + norms + CSR (src+dst) build + segments ----------------
__global__ __launch_bounds__(1024) void k_build(const int* __restrict__ edges,
                                                float* __restrict__ rs_out,
                                                float* __restrict__ rs_in,
                                                int* __restrict__ row_ofs,
                                                int* __restrict__ csr_src,
                                                int* __restrict__ csr_dst,
                                                int* __restrict__ seg) {
    int g = blockIdx.x;
    int tid = threadIdx.x;
    const int* src = edges + (size_t)g * 2 * NE;
    const int* dst = src + NE;

    __shared__ int degO[NN], degI[NN];
    __shared__ int scanA[NN], scanB[NN];
    __shared__ int fill[NN];
    __shared__ int csr_lds[NE];          // 32 KB
    __shared__ int dst_lds[NE];          // 32 KB

    for (int i = tid; i < NN; i += 1024) { degO[i] = 0; degI[i] = 0; }
    __syncthreads();
    for (int u = tid; u < NE / 4; u += 1024) {
        int4 s = ((const int4*)src)[u];
        int4 d = ((const int4*)dst)[u];
        atomicAdd(&degO[s.x], 1); atomicAdd(&degO[s.y], 1);
        atomicAdd(&degO[s.z], 1); atomicAdd(&degO[s.w], 1);
        atomicAdd(&degI[d.x], 1); atomicAdd(&degI[d.y], 1);
        atomicAdd(&degI[d.z], 1); atomicAdd(&degI[d.w], 1);
    }
    __syncthreads();
    for (int i = tid; i < NN; i += 1024) {
        int dO = degO[i], dI = degI[i];
        rs_out[g * NN + i] = rsqrtf((float)max(dO, 1));
        rs_in [g * NN + i] = rsqrtf((float)max(dI, 1));
        scanA[i] = dI;
    }
    __syncthreads();
    int* sA = scanA; int* sB = scanB;
    for (int off = 1; off < NN; off <<= 1) {
        for (int i = tid; i < NN; i += 1024) {
            int v = sA[i];
            if (i >= off) v += sA[i - off];
            sB[i] = v;
        }
        __syncthreads();
        int* t = sA; sA = sB; sB = t;
    }
    for (int i = tid; i < NN; i += 1024) {
        int excl = (i == 0) ? 0 : sA[i - 1];
        fill[i] = excl;
        row_ofs[g * 513 + i] = excl;
    }
    if (tid == 0) row_ofs[g * 513 + NN] = sA[NN - 1];
    if (tid < NSEG) {
        int target = tid * (NE / NSEG);
        int lo = 0, hi = NN;
        while (lo < hi) {
            int mid = (lo + hi) >> 1;
            int ex = (mid == 0) ? 0 : sA[mid - 1];
            if (ex >= target) hi = mid; else lo = mid + 1;
        }
        seg[g * (NSEG + 1) + tid] = lo;
    }
    if (tid == 0) seg[g * (NSEG + 1) + NSEG] = NN;
    __syncthreads();
    for (int u = tid; u < NE / 4; u += 1024) {
        int4 s = ((const int4*)src)[u];
        int4 d = ((const int4*)dst)[u];
        int p0 = atomicAdd(&fill[d.x], 1); csr_lds[p0] = s.x; dst_lds[p0] = d.x;
        int p1 = atomicAdd(&fill[d.y], 1); csr_lds[p1] = s.y; dst_lds[p1] = d.y;
        int p2 = atomicAdd(&fill[d.z], 1); csr_lds[p2] = s.z; dst_lds[p2] = d.z;
        int p3 = atomicAdd(&fill[d.w], 1); csr_lds[p3] = s.w; dst_lds[p3] = d.w;
    }
    __syncthreads();
    for (int u = tid; u < NE / 4; u += 1024) {
        ((int4*)(csr_src + (size_t)g * NE))[u] = ((const int4*)csr_lds)[u];
        ((int4*)(csr_dst + (size_t)g * NE))[u] = ((const int4*)dst_lds)[u];
    }
    if (g == NG - 1 && tid < 8) {
        csr_src[(size_t)NG * NE + tid] = 0;
        csr_dst[(size_t)NG * NE + tid] = 0;
    }
}

// ---------------- K0: pack W0,W1 into MFMA B-fragment order, bf16 hi/lo ----------------
// WP layout: [which*2 + hi/lo][32 (nt*4+kk)][64 lanes][8 bf16]; 16 B per lane.
__global__ __launch_bounds__(64) void k_packW(const float* __restrict__ W0,
                                              const float* __restrict__ W1,
                                              unsigned short* __restrict__ WP) {
    int b = blockIdx.x;          // 0..63: which = b>>5, tile = b&31
    int which = b >> 5;
    int t = b & 31;
    int nt = t >> 2, kk = t & 3;
    int lane = threadIdx.x;
    const float* W = which ? W1 : W0;
    int n = nt * 16 + (lane & 15);
    int k0 = kk * 32 + (lane >> 4) * 8;
    unsigned short* dh = WP + ((size_t)which * 2 + 0) * 16384 + ((size_t)t * 64 + lane) * 8;
    unsigned short* dl = WP + ((size_t)which * 2 + 1) * 16384 + ((size_t)t * 64 + lane) * 8;
#pragma unroll
    for (int j = 0; j < 8; j++) {
        float v = W[(size_t)(k0 + j) * FH + n];
        unsigned short h = f2bf(v);
        dh[j] = h;
        dl[j] = f2bf(v - bf2f(h));
    }
}

// ---------------- K2/K4: Y = (X @ W) * rs_row  (bf16-split MFMA) ----------------
// Block = 64 rows, 4 waves x 16 rows. X staged in LDS as bf16 hi/lo (pad +8).
// W read from pre-packed global fragments (L1/L2-resident, coalesced 16B/lane).
// Split product: Ah*Bh + Al*Bh + Ah*Bl  (Al*Bl ~ 2^-18, dropped).
#define XPITCH 136
__global__ __launch_bounds__(256) void k_gemm(const float* __restrict__ X,
                                              const unsigned short* __restrict__ WPh,
                                              const unsigned short* __restrict__ WPl,
                                              const float* __restrict__ rs,
                                              float* __restrict__ Y) {
    __shared__ unsigned short xh[64 * XPITCH];   // 17 KB
    __shared__ unsigned short xl[64 * XPITCH];   // 17 KB
    int tid = threadIdx.x;
    size_t r0 = (size_t)blockIdx.x * 64;

    const float4* Xv = (const float4*)(X + r0 * FH);
#pragma unroll
    for (int i = 0; i < 8; i++) {
        int u = tid + i * 256;                 // 2048 float4 = 64x128
        int row = u >> 5, c4 = (u & 31) * 4;
        float4 v = Xv[u];
        int off = row * XPITCH + c4;
        unsigned short h0 = f2bf(v.x), h1 = f2bf(v.y), h2 = f2bf(v.z), h3 = f2bf(v.w);
        xh[off + 0] = h0; xh[off + 1] = h1; xh[off + 2] = h2; xh[off + 3] = h3;
        xl[off + 0] = f2bf(v.x - bf2f(h0));
        xl[off + 1] = f2bf(v.y - bf2f(h1));
        xl[off + 2] = f2bf(v.z - bf2f(h2));
        xl[off + 3] = f2bf(v.w - bf2f(h3));
    }
    __syncthreads();

    int lane = tid & 63, w = tid >> 6;
    int quad = lane >> 4, m = lane & 15;
    int arow = w * 16 + m;

    f4v acc[8];
#pragma unroll
    for (int nt = 0; nt < 8; nt++) acc[nt] = (f4v){0.f, 0.f, 0.f, 0.f};

#pragma unroll
    for (int kk = 0; kk < 4; kk++) {
        s8v ah = *(const s8v*)&xh[arow * XPITCH + kk * 32 + quad * 8];
        s8v al = *(const s8v*)&xl[arow * XPITCH + kk * 32 + quad * 8];
#pragma unroll
        for (int nt = 0; nt < 8; nt++) {
            s8v bh = *(const s8v*)(WPh + ((size_t)(nt * 4 + kk) * 64 + lane) * 8);
            s8v bl = *(const s8v*)(WPl + ((size_t)(nt * 4 + kk) * 64 + lane) * 8);
            acc[nt] = __builtin_amdgcn_mfma_f32_16x16x32_bf16(ah, bh, acc[nt], 0, 0, 0);
            acc[nt] = __builtin_amdgcn_mfma_f32_16x16x32_bf16(al, bh, acc[nt], 0, 0, 0);
            acc[nt] = __builtin_amdgcn_mfma_f32_16x16x32_bf16(ah, bl, acc[nt], 0, 0, 0);
        }
    }

    // epilogue: D[row=quad*4+r][col=m], scale by rs[row]
    int orow = w * 16 + quad * 4;
    float4 rsv = *(const float4*)(rs + r0 + orow);
#pragma unroll
    for (int nt = 0; nt < 8; nt++) {
        Y[(r0 + orow + 0) * FH + nt * 16 + m] = acc[nt][0] * rsv.x;
        Y[(r0 + orow + 1) * FH + nt * 16 + m] = acc[nt][1] * rsv.y;
        Y[(r0 + orow + 2) * FH + nt * 16 + m] = acc[nt][2] * rsv.z;
        Y[(r0 + orow + 3) * FH + nt * 16 + m] = acc[nt][3] * rsv.w;
    }
}

// ---------------- K3: flat edge-quad gather ----------------
__global__ __launch_bounds__(256) void k_gather(const float* __restrict__ Y,
                                                const int* __restrict__ row_ofs,
                                                const int* __restrict__ csr_src,
                                                const int* __restrict__ csr_dst,
                                                const int* __restrict__ seg,
                                                const float* __restrict__ rs_in,
                                                const float* __restrict__ bias,
                                                float* __restrict__ H) {
    int g  = blockIdx.x;
    int fq = blockIdx.y;
    int tid = threadIdx.x;
    int l4  = tid & 3;
    int grp = tid >> 2;

    __shared__ float ys[NN][FQ];
    __shared__ float rsin_s[NN];

    const float* Yg = Y + (size_t)g * NN * FH + fq * FQ;
#pragma unroll
    for (int i = 0; i < 8; i++) {
        int u = tid + i * 256;
        int r = u >> 2, c = u & 3;
        *(float4*)&ys[r][c * 4] = *(const float4*)(Yg + (size_t)r * FH + c * 4);
    }
    for (int i = tid; i < NN; i += 256) rsin_s[i] = rs_in[g * NN + i];
    __syncthreads();

    int d0 = seg[g * (NSEG + 1) + grp], d1 = seg[g * (NSEG + 1) + grp + 1];
    if (d0 >= d1) return;

    const int* ro = row_ofs + g * 513;
    const int* cs = csr_src + (size_t)g * NE;
    const int* cd = csr_dst + (size_t)g * NE;
    int e0 = ro[d0], eEnd = ro[d1];
    float4 bv = *(const float4*)(bias + fq * FQ + l4 * 4);
    float4 rb;
    rb.x = fmaxf(bv.x, 0.f); rb.y = fmaxf(bv.y, 0.f);
    rb.z = fmaxf(bv.z, 0.f); rb.w = fmaxf(bv.w, 0.f);
    float* Hg = H + (size_t)g * NN * FH + fq * FQ + l4 * 4;

    int d = d0;
    float4 acc = make_float4(0.f, 0.f, 0.f, 0.f);
    int e = e0 & ~3;
    int4 S = *(const int4*)(cs + e);
    int4 D = *(const int4*)(cd + e);
    for (; e < eEnd; e += 4) {
        int4 Sn = *(const int4*)(cs + e + 4);
        int4 Dn = *(const int4*)(cd + e + 4);
        float4 y0 = *(float4*)&ys[S.x][l4 * 4];
        float4 y1 = *(float4*)&ys[S.y][l4 * 4];
        float4 y2 = *(float4*)&ys[S.z][l4 * 4];
        float4 y3 = *(float4*)&ys[S.w][l4 * 4];
#define STEP(J, DJ, YJ)                                                     \
        {                                                                   \
            int idx = e + (J);                                              \
            bool valid = (idx >= e0) & (idx < eEnd);                        \
            if (valid && (DJ) != d) {                                       \
                float r = rsin_s[d];                                        \
                float4 h;                                                   \
                h.x = fmaxf(fmaf(r, acc.x, bv.x), 0.f);                     \
                h.y = fmaxf(fmaf(r, acc.y, bv.y), 0.f);                     \
                h.z = fmaxf(fmaf(r, acc.z, bv.z), 0.f);                     \
                h.w = fmaxf(fmaf(r, acc.w, bv.w), 0.f);                     \
                *(float4*)(Hg + (size_t)d * FH) = h;                        \
                for (int dd = d + 1; dd < (DJ); dd++)                       \
                    *(float4*)(Hg + (size_t)dd * FH) = rb;                  \
                d = (DJ);                                                   \
                acc = make_float4(0.f, 0.f, 0.f, 0.f);                      \
            }                                                               \
            if (valid) f4acc(acc, YJ);                                      \
        }
        STEP(0, D.x, y0) STEP(1, D.y, y1) STEP(2, D.z, y2) STEP(3, D.w, y3)
#undef STEP
        S = Sn; D = Dn;
    }
    {
        float r = rsin_s[d];
        float4 h;
        h.x = fmaxf(fmaf(r, acc.x, bv.x), 0.f);
        h.y = fmaxf(fmaf(r, acc.y, bv.y), 0.f);
        h.z = fmaxf(fmaf(r, acc.z, bv.z), 0.f);
        h.w = fmaxf(fmaf(r, acc.w, bv.w), 0.f);
        *(float4*)(Hg + (size_t)d * FH) = h;
        for (int dd = d + 1; dd < d1; dd++)
            *(float4*)(Hg + (size_t)dd * FH) = rb;
    }
}

// ---------------- K5: flat edge-quad gather2 + fused node-sum -> emb slice ----------------
__global__ __launch_bounds__(256) void k_gather_mean(const float* __restrict__ Y,
                                                     const int* __restrict__ row_ofs,
                                                     const int* __restrict__ csr_src,
                                                     const int* __restrict__ csr_dst,
                                                     const int* __restrict__ seg,
                                                     const float* __restrict__ rs_in,
                                                     const float* __restrict__ bias,
                                                     float* __restrict__ emb) {
    int g  = blockIdx.x;
    int fq = blockIdx.y;
    int tid = threadIdx.x;
    int l4  = tid & 3;
    int grp = tid >> 2;

    __shared__ float ys[NN][FQ];
    __shared__ float rsin_s[NN];
    __shared__ float4 red[NSEG][4];

    const float* Yg = Y + (size_t)g * NN * FH + fq * FQ;
#pragma unroll
    for (int i = 0; i < 8; i++) {
        int u = tid + i * 256;
        int r = u >> 2, c = u & 3;
        *(float4*)&ys[r][c * 4] = *(const float4*)(Yg + (size_t)r * FH + c * 4);
    }
    for (int i = tid; i < NN; i += 256) rsin_s[i] = rs_in[g * NN + i];
    __syncthreads();

    int d0 = seg[g * (NSEG + 1) + grp], d1 = seg[g * (NSEG + 1) + grp + 1];

    const int* ro = row_ofs + g * 513;
    const int* cs = csr_src + (size_t)g * NE;
    const int* cd = csr_dst + (size_t)g * NE;
    float4 bv = *(const float4*)(bias + fq * FQ + l4 * 4);
    float4 rb;
    rb.x = fmaxf(bv.x, 0.f); rb.y = fmaxf(bv.y, 0.f);
    rb.z = fmaxf(bv.z, 0.f); rb.w = fmaxf(bv.w, 0.f);

    float4 sum = make_float4(0.f, 0.f, 0.f, 0.f);
    if (d0 < d1) {
        int e0 = ro[d0], eEnd = ro[d1];
        int d = d0;
        float4 acc = make_float4(0.f, 0.f, 0.f, 0.f);
        int e = e0 & ~3;
        int4 S = *(const int4*)(cs + e);
        int4 D = *(const int4*)(cd + e);
        for (; e < eEnd; e += 4) {
            int4 Sn = *(const int4*)(cs + e + 4);
            int4 Dn = *(const int4*)(cd + e + 4);
            float4 y0 = *(float4*)&ys[S.x][l4 * 4];
            float4 y1 = *(float4*)&ys[S.y][l4 * 4];
            float4 y2 = *(float4*)&ys[S.z][l4 * 4];
            float4 y3 = *(float4*)&ys[S.w][l4 * 4];
#define STEP(J, DJ, YJ)                                                     \
            {                                                               \
                int idx = e + (J);                                          \
                bool valid = (idx >= e0) & (idx < eEnd);                    \
                if (valid && (DJ) != d) {                                   \
                    float r = rsin_s[d];                                    \
                    sum.x += fmaxf(fmaf(r, acc.x, bv.x), 0.f);              \
                    sum.y += fmaxf(fmaf(r, acc.y, bv.y), 0.f);              \
                    sum.z += fmaxf(fmaf(r, acc.z, bv.z), 0.f);              \
                    sum.w += fmaxf(fmaf(r, acc.w, bv.w), 0.f);              \
                    float gf = (float)((DJ) - d - 1);                       \
                    sum.x += gf * rb.x; sum.y += gf * rb.y;                 \
                    sum.z += gf * rb.z; sum.w += gf * rb.w;                 \
                    d = (DJ);                                               \
                    acc = make_float4(0.f, 0.f, 0.f, 0.f);                  \
                }                                                           \
                if (valid) f4acc(acc, YJ);                                  \
            }
            STEP(0, D.x, y0) STEP(1, D.y, y1) STEP(2, D.z, y2) STEP(3, D.w, y3)
#undef STEP
            S = Sn; D = Dn;
        }
        {
            float r = rsin_s[d];
            sum.x += fmaxf(fmaf(r, acc.x, bv.x), 0.f);
            sum.y += fmaxf(fmaf(r, acc.y, bv.y), 0.f);
            sum.z += fmaxf(fmaf(r, acc.z, bv.z), 0.f);
            sum.w += fmaxf(fmaf(r, acc.w, bv.w), 0.f);
            float gf = (float)(d1 - 1 - d);
            sum.x += gf * rb.x; sum.y += gf * rb.y;
            sum.z += gf * rb.z; sum.w += gf * rb.w;
        }
    }

    red[grp][l4] = sum;
    __syncthreads();
    if (tid < 4) {
        float4 t = red[0][tid];
#pragma unroll
        for (int j = 1; j < NSEG; j++) f4acc(t, red[j][tid]);
        *(float4*)(emb + (size_t)g * FH + fq * FQ + tid * 4) = t;
    }
}

// ---------------- K6: z = emb/512 @ Wt + bt; BN eval; relu ----------------
__global__ __launch_bounds__(128) void k_head(const float* __restrict__ emb,
                                              const float* __restrict__ Wt,
                                              const float* __restrict__ bt,
                                              const float* __restrict__ gamma,
                                              const float* __restrict__ beta,
                                              const float* __restrict__ rmean,
                                              const float* __restrict__ rvar,
                                              float* __restrict__ out) {
    int g = blockIdx.x;
    int j = threadIdx.x;
    __shared__ float e[FH];
    e[j] = emb[(size_t)g * FH + j] * (1.0f / (float)NN);
    __syncthreads();
    float acc = bt[j];
#pragma unroll 8
    for (int k = 0; k < FH; k++) acc += e[k] * Wt[(size_t)k * FH + j];
    float z = gamma[j] * (acc - rmean[j]) * rsqrtf(rvar[j] + BN_EPS) + beta[j];
    out[g * FH + j] = fmaxf(z, 0.f);
}

extern "C" void kernel_launch(void* const* d_in, const int* in_sizes, int n_in,
                              void* d_out, int out_size, void* d_ws, size_t ws_size,
                              hipStream_t stream) {
    const float* feats = (const float*)d_in[0];
    const int*   edges = (const int*)d_in[1];
    const float* W0    = (const float*)d_in[2];
    const float* b0    = (const float*)d_in[3];
    const float* W1    = (const float*)d_in[4];
    const float* b1    = (const float*)d_in[5];
    const float* Wt    = (const float*)d_in[6];
    const float* bt    = (const float*)d_in[7];
    const float* gamma = (const float*)d_in[8];
    const float* beta  = (const float*)d_in[9];
    const float* rmean = (const float*)d_in[10];
    const float* rvar  = (const float*)d_in[11];
    float* out = (float*)d_out;

    // workspace layout
    char* w = (char*)d_ws;
    float* rs_out  = (float*)w;   w += sizeof(float) * NG * NN;
    float* rs_in   = (float*)w;   w += sizeof(float) * NG * NN;
    int*   row_ofs = (int*)w;     w += sizeof(int) * NG * 520;
    int*   seg     = (int*)w;     w += sizeof(int) * NG * (NSEG + 1) + 64;
    int*   csr_src = (int*)w;     w += sizeof(int) * ((size_t)NG * NE + 16);
    int*   csr_dst = (int*)w;     w += sizeof(int) * ((size_t)NG * NE + 16);
    unsigned short* WP = (unsigned short*)w;  w += sizeof(unsigned short) * 4 * 16384; // 128 KB
    float* Y       = (float*)w;   w += sizeof(float) * (size_t)NG * NN * FH;
    float* H1      = (float*)w;   w += sizeof(float) * (size_t)NG * NN * FH;
    float* emb     = (float*)w;   w += sizeof(float) * NG * FH;

    unsigned short* WPh0 = WP;
    unsigned short* WPl0 = WP + 16384;
    unsigned short* WPh1 = WP + 32768;
    unsigned short* WPl1 = WP + 49152;

    k_build<<<NG, 1024, 0, stream>>>(edges, rs_out, rs_in, row_ofs, csr_src, csr_dst, seg);

    k_packW<<<64, 64, 0, stream>>>(W0, W1, WP);

    k_gemm<<<(NG * NN) / 64, 256, 0, stream>>>(feats, WPh0, WPl0, rs_out, Y);

    k_gather<<<dim3(NG, FH / FQ), 256, 0, stream>>>(Y, row_ofs, csr_src, csr_dst, seg, rs_in, b0, H1);

    k_gemm<<<(NG * NN) / 64, 256, 0, stream>>>(H1, WPh1, WPl1, rs_out, Y);

    k_gather_mean<<<dim3(NG, FH / FQ), 256, 0, stream>>>(Y, row_ofs, csr_src, csr_dst, seg, rs_in, b1, emb);

    k_head<<<NG, 128, 0, stream>>>(emb, Wt, bt, gamma, beta, rmean, rvar, out);

    (void)in_sizes; (void)n_in; (void)out_size; (void)ws_size;
}